// Round 2
// baseline (527.748 us; speedup 1.0000x reference)
//
#include <hip/hip_runtime.h>

// MultiHeadSelfAttention: B=4, S=2048, E=1024, H=16, Dh=64.
// Stage 1: qkv_gemm  -> q,k bf16 head-major [bh][s][d]; V TRANSPOSED [bh][d][s]
// Stage 2: attn      -> swapped-QK^T flash attention, barrier-free,
//                       register-double-buffered K/V prefetch, XCD-sliced blocks
// Stage 3: out_gemm  -> @ Wo^T + bo -> d_out (fp32)

typedef __bf16 bf16;
typedef __attribute__((ext_vector_type(8))) short short8;
typedef __attribute__((ext_vector_type(4))) float floatx4;
typedef __attribute__((ext_vector_type(2))) unsigned int uintx2;

#define MFMA16(a, b, c) __builtin_amdgcn_mfma_f32_16x16x32_bf16((a), (b), (c), 0, 0, 0)

#define LDS_STRIDE 56   // 128x32 tile rows padded 32->56 elems (112 B): 16B-aligned
#define ATT_STRIDE 136  // P rows: 128 cols padded ->136 shorts (272 B): 16B-aligned

__device__ __forceinline__ float fast_exp2(float x) {
    float r;
    asm("v_exp_f32 %0, %1" : "=v"(r) : "v"(x));
    return r;
}
__device__ __forceinline__ unsigned int cvt_pk_bf16(float lo, float hi) {
    unsigned int r;
    asm("v_cvt_pk_bf16_f32 %0, %1, %2" : "=v"(r) : "v"(lo), "v"(hi));
    return r;
}

// 8 contiguous elements -> 8 bf16 (as short8 bit pattern)
__device__ __forceinline__ short8 frag8(const bf16* __restrict__ p) {
    return *(const short8*)p;
}
__device__ __forceinline__ short8 frag8(const float* __restrict__ p) {
    const floatx4 a = *(const floatx4*)p;
    const floatx4 b = *(const floatx4*)(p + 4);
    short8 r;
#pragma unroll
    for (int j = 0; j < 4; j++) {
        r[j]     = __builtin_bit_cast(short, (bf16)a[j]);
        r[4 + j] = __builtin_bit_cast(short, (bf16)b[j]);
    }
    return r;
}

// ---------------------------------------------------------------------------
// 128x128-tile GEMM core: C[m][n] = sum_k A[m][k] * B[n][k]  (both K-contiguous)
// 256 threads = 4 waves (2x2 of 64x64), BK=32, single-buffered LDS.
// ---------------------------------------------------------------------------
template <typename TA, typename TB>
__device__ __forceinline__ void gemm128_core(
    const TA* __restrict__ A, const TB* __restrict__ B, int K,
    int m0, int n0, short* As, short* Bs, floatx4 acc[4][4])
{
    const int tid  = threadIdx.x;
    const int lane = tid & 63;
    const int w    = tid >> 6;
    const int wm   = w >> 1, wn = w & 1;
    const int g    = lane >> 4, c = lane & 15;
    const int lrow = tid >> 2;        // 0..63
    const int lc8  = (tid & 3) * 8;   // 0,8,16,24

#pragma unroll
    for (int mi = 0; mi < 4; mi++)
#pragma unroll
        for (int ni = 0; ni < 4; ni++)
            acc[mi][ni] = (floatx4){0.f, 0.f, 0.f, 0.f};

    for (int k0 = 0; k0 < K; k0 += 32) {
        *(short8*)(As + lrow * LDS_STRIDE + lc8) =
            frag8(A + (size_t)(m0 + lrow) * K + k0 + lc8);
        *(short8*)(As + (lrow + 64) * LDS_STRIDE + lc8) =
            frag8(A + (size_t)(m0 + lrow + 64) * K + k0 + lc8);
        *(short8*)(Bs + lrow * LDS_STRIDE + lc8) =
            frag8(B + (size_t)(n0 + lrow) * K + k0 + lc8);
        *(short8*)(Bs + (lrow + 64) * LDS_STRIDE + lc8) =
            frag8(B + (size_t)(n0 + lrow + 64) * K + k0 + lc8);
        __syncthreads();

        short8 af[4], bfr[4];
#pragma unroll
        for (int mi = 0; mi < 4; mi++)
            af[mi] = *(const short8*)(As + (wm * 64 + mi * 16 + c) * LDS_STRIDE + g * 8);
#pragma unroll
        for (int ni = 0; ni < 4; ni++)
            bfr[ni] = *(const short8*)(Bs + (wn * 64 + ni * 16 + c) * LDS_STRIDE + g * 8);
#pragma unroll
        for (int mi = 0; mi < 4; mi++)
#pragma unroll
            for (int ni = 0; ni < 4; ni++)
                acc[mi][ni] = MFMA16(af[mi], bfr[ni], acc[mi][ni]);
        __syncthreads();
    }
}

// ---------------------------------------------------------------------------
// Stage 1: q/k/v = x @ W{q,k,v}^T + b, scattered to head-major bf16.
// q,k: [bh][s][64].  v: TRANSPOSED [bh][d][2048].
// grid (8, 64, 3), block 256
// ---------------------------------------------------------------------------
__global__ __launch_bounds__(256) void qkv_gemm(
    const float* __restrict__ X,
    const float* __restrict__ Wq, const float* __restrict__ Wk, const float* __restrict__ Wv,
    const float* __restrict__ bq, const float* __restrict__ bk, const float* __restrict__ bv,
    bf16* __restrict__ qkv)
{
    __shared__ __align__(16) short As[128 * LDS_STRIDE];
    __shared__ __align__(16) short Bs[128 * LDS_STRIDE];

    const int z = blockIdx.z;
    const float* W    = (z == 0) ? Wq : (z == 1) ? Wk : Wv;
    const float* bias = (z == 0) ? bq : (z == 1) ? bk : bv;
    bf16* outz = qkv + (size_t)z * (8192u * 1024u);

    const int m0 = blockIdx.y * 128;
    const int n0 = blockIdx.x * 128;

    floatx4 acc[4][4];
    gemm128_core(X, W, 1024, m0, n0, As, Bs, acc);

    const int lane = threadIdx.x & 63;
    const int w = threadIdx.x >> 6;
    const int wm = w >> 1, wn = w & 1;
    const int g = lane >> 4, c = lane & 15;

#pragma unroll
    for (int ni = 0; ni < 4; ni++) {
        const int n = n0 + wn * 64 + ni * 16 + c;
        const float bb = bias[n];
        const int h = n >> 6, d = n & 63;
#pragma unroll
        for (int mi = 0; mi < 4; mi++) {
#pragma unroll
            for (int r = 0; r < 4; r++) {
                const int m = m0 + wm * 64 + mi * 16 + g * 4 + r;
                const int b = m >> 11, s = m & 2047;
                const size_t idx = (z == 2)
                    ? ((((size_t)((b << 4) | h)) * 64 + d) * 2048 + s)    // V^T
                    : ((((size_t)((b << 4) | h)) * 2048 + s) * 64 + d);   // Q,K
                outz[idx] = (bf16)(acc[mi][ni][r] + bb);
            }
        }
    }
}

// ---------------------------------------------------------------------------
// Stage 2: flash attention, swapped QK^T, barrier-free, reg-prefetched K/V.
// grid (16, 64), block 256.  Each wave owns 32 queries; 16 K-blocks of 128.
// ---------------------------------------------------------------------------
__device__ __forceinline__ void attn_step(
    const bf16* __restrict__ Kp, const bf16* __restrict__ Vt,
    short* __restrict__ Pw, const short8 (&qf)[2][2],
    const short8 (&kfC)[16], const short8 (&vfC)[16],
    short8 (&kfN)[16], short8 (&vfN)[16],
    int k0, int kn,
    floatx4 (&o)[2][4], float (&m_run)[2], float (&l_run)[2],
    int lane, int g, int c)
{
    const float C2 = 0.04508422002778f;  // (1/sqrt(1024)) * log2(e)

    // S^T = K Q^T (swapped): lane (g,c) holds S[key=16ni+4g+r][query=qb*16+c]
    floatx4 sAcc[2][8];
#pragma unroll
    for (int qb = 0; qb < 2; qb++)
#pragma unroll
        for (int ni = 0; ni < 8; ni++)
            sAcc[qb][ni] = (floatx4){0.f, 0.f, 0.f, 0.f};
#pragma unroll
    for (int ks = 0; ks < 2; ks++)
#pragma unroll
        for (int qb = 0; qb < 2; qb++)
#pragma unroll
            for (int ni = 0; ni < 8; ni++)
                sAcc[qb][ni] = MFMA16(kfC[ks * 8 + ni], qf[qb][ks], sAcc[qb][ni]);

    // prefetch next K/V tiles into registers: latency hides under softmax+PV
#pragma unroll
    for (int ks = 0; ks < 2; ks++)
#pragma unroll
        for (int ni = 0; ni < 8; ni++)
            kfN[ks * 8 + ni] = *(const short8*)(Kp + (size_t)(kn + ni * 16 + c) * 64
                                                   + ks * 32 + g * 8);
#pragma unroll
    for (int ks2 = 0; ks2 < 4; ks2++)
#pragma unroll
        for (int di = 0; di < 4; di++)
            vfN[ks2 * 4 + di] = *(const short8*)(Vt + (size_t)(di * 16 + c) * 2048
                                                    + kn + ks2 * 32 + g * 8);

    // online softmax: lane (g,c) holds 32 scores of query qb*16+c
    float alpha[2];
#pragma unroll
    for (int qb = 0; qb < 2; qb++) {
        floatx4 mv = sAcc[qb][0];
#pragma unroll
        for (int ni = 1; ni < 8; ni++)
#pragma unroll
            for (int r = 0; r < 4; r++) mv[r] = fmaxf(mv[r], sAcc[qb][ni][r]);
        float mx = fmaxf(fmaxf(mv[0], mv[1]), fmaxf(mv[2], mv[3]));
        mx = fmaxf(mx, __shfl_xor(mx, 16));
        mx = fmaxf(mx, __shfl_xor(mx, 32));
        const float mnew = fmaxf(m_run[qb], mx * C2);
        alpha[qb] = fast_exp2(m_run[qb] - mnew);
        m_run[qb] = mnew;

        floatx4 sv = {0.f, 0.f, 0.f, 0.f};
#pragma unroll
        for (int ni = 0; ni < 8; ni++)
#pragma unroll
            for (int r = 0; r < 4; r++) {
                const float p = fast_exp2(fmaf(sAcc[qb][ni][r], C2, -mnew));
                sAcc[qb][ni][r] = p;
                sv[r] += p;
            }
        float sum = (sv[0] + sv[1]) + (sv[2] + sv[3]);
        sum += __shfl_xor(sum, 16);
        sum += __shfl_xor(sum, 32);
        l_run[qb] = l_run[qb] * alpha[qb] + sum;

        // pack P -> bf16 pairs, one b64 store per 16-key block (wave-private)
#pragma unroll
        for (int ni = 0; ni < 8; ni++) {
            uintx2 pk;
            pk[0] = cvt_pk_bf16(sAcc[qb][ni][0], sAcc[qb][ni][1]);
            pk[1] = cvt_pk_bf16(sAcc[qb][ni][2], sAcc[qb][ni][3]);
            *(uintx2*)(Pw + (qb * 16 + c) * ATT_STRIDE + ni * 16 + g * 4) = pk;
        }
    }

    // rescale O by per-row alpha (row 4g+r's stats live at lane with c == 4g+r)
#pragma unroll
    for (int mi = 0; mi < 2; mi++)
#pragma unroll
        for (int r = 0; r < 4; r++) {
            const int src = (lane & 48) | (g * 4 + r);
            const float a = __shfl(alpha[mi], src);
#pragma unroll
            for (int di = 0; di < 4; di++) o[mi][di][r] *= a;
        }

    // O += P V   (A = P from wave-private LDS, B = V^T frags from registers)
#pragma unroll
    for (int ks2 = 0; ks2 < 4; ks2++) {
        short8 pf[2];
#pragma unroll
        for (int mi = 0; mi < 2; mi++)
            pf[mi] = *(const short8*)(Pw + (mi * 16 + c) * ATT_STRIDE + ks2 * 32 + g * 8);
#pragma unroll
        for (int mi = 0; mi < 2; mi++)
#pragma unroll
            for (int di = 0; di < 4; di++)
                o[mi][di] = MFMA16(pf[mi], vfC[ks2 * 4 + di], o[mi][di]);
    }
}

__global__ __launch_bounds__(256, 1) void attn_kernel(
    const bf16* __restrict__ qkv, bf16* __restrict__ attn_out)
{
    __shared__ __align__(16) short Pl[4 * 32 * ATT_STRIDE];   // 34.8 KB

    // XCD-sliced remap: each XCD owns 8 whole heads -> K/V stay L2-resident.
    const int linear = blockIdx.y * gridDim.x + blockIdx.x;   // dispatch order id
    const int slot = linear >> 3;
    const int bh = (linear & 7) * 8 + (slot >> 4);            // 0..63
    const int q0 = (slot & 15) * 128;

    const size_t HSTRIDE = 2048u * 64u;
    const bf16* __restrict__ Q  = qkv + (size_t)bh * HSTRIDE;
    const bf16* __restrict__ Kp = qkv + 8192u * 1024u + (size_t)bh * HSTRIDE;
    const bf16* __restrict__ Vt = qkv + 2u * 8192u * 1024u + (size_t)bh * HSTRIDE; // [64][2048]

    const int tid  = threadIdx.x;
    const int lane = tid & 63;
    const int w    = tid >> 6;
    const int g    = lane >> 4, c = lane & 15;
    short* __restrict__ Pw = Pl + w * (32 * ATT_STRIDE);

    // Q fragments resident in regs
    short8 qf[2][2];
#pragma unroll
    for (int qb = 0; qb < 2; qb++)
#pragma unroll
        for (int ks = 0; ks < 2; ks++)
            qf[qb][ks] = *(const short8*)(Q + (size_t)(q0 + w * 32 + qb * 16 + c) * 64
                                            + ks * 32 + g * 8);

    floatx4 o[2][4];
#pragma unroll
    for (int mi = 0; mi < 2; mi++)
#pragma unroll
        for (int di = 0; di < 4; di++)
            o[mi][di] = (floatx4){0.f, 0.f, 0.f, 0.f};
    float m_run[2] = {-1e30f, -1e30f};
    float l_run[2] = {0.f, 0.f};

    // double-buffered K/V fragment registers
    short8 kfA[16], vfA[16], kfB[16], vfB[16];
#pragma unroll
    for (int ks = 0; ks < 2; ks++)
#pragma unroll
        for (int ni = 0; ni < 8; ni++)
            kfA[ks * 8 + ni] = *(const short8*)(Kp + (size_t)(ni * 16 + c) * 64
                                                   + ks * 32 + g * 8);
#pragma unroll
    for (int ks2 = 0; ks2 < 4; ks2++)
#pragma unroll
        for (int di = 0; di < 4; di++)
            vfA[ks2 * 4 + di] = *(const short8*)(Vt + (size_t)(di * 16 + c) * 2048
                                                    + ks2 * 32 + g * 8);

    for (int kb = 0; kb < 16; kb += 2) {
        attn_step(Kp, Vt, Pw, qf, kfA, vfA, kfB, vfB,
                  kb * 128, (kb + 1) * 128, o, m_run, l_run, lane, g, c);
        attn_step(Kp, Vt, Pw, qf, kfB, vfB, kfA, vfA,
                  (kb + 1) * 128, ((kb + 2) & 15) * 128, o, m_run, l_run, lane, g, c);
    }

    // epilogue: O /= l (redistribute l to O's row layout), write bf16
    const int b = bh >> 4, h = bh & 15;
#pragma unroll
    for (int mi = 0; mi < 2; mi++) {
#pragma unroll
        for (int r = 0; r < 4; r++) {
            const int src = (lane & 48) | (g * 4 + r);
            const float linv = 1.0f / __shfl(l_run[mi], src);
            const int srow = q0 + w * 32 + mi * 16 + g * 4 + r;
#pragma unroll
            for (int di = 0; di < 4; di++) {
                attn_out[((size_t)(b * 2048 + srow)) * 1024 + h * 64 + di * 16 + c] =
                    (bf16)(o[mi][di][r] * linv);
            }
        }
    }
}

// ---------------------------------------------------------------------------
// Stage 3: out = attn @ Wo^T + bo -> fp32. grid (8, 64).
// ---------------------------------------------------------------------------
__global__ __launch_bounds__(256) void out_gemm(
    const bf16* __restrict__ A, const float* __restrict__ Wo,
    const float* __restrict__ bo, float* __restrict__ C)
{
    __shared__ __align__(16) short As[128 * LDS_STRIDE];
    __shared__ __align__(16) short Bs[128 * LDS_STRIDE];

    const int m0 = blockIdx.y * 128;
    const int n0 = blockIdx.x * 128;

    floatx4 acc[4][4];
    gemm128_core(A, Wo, 1024, m0, n0, As, Bs, acc);

    const int lane = threadIdx.x & 63;
    const int w = threadIdx.x >> 6;
    const int wm = w >> 1, wn = w & 1;
    const int g = lane >> 4, c = lane & 15;

#pragma unroll
    for (int ni = 0; ni < 4; ni++) {
        const int n = n0 + wn * 64 + ni * 16 + c;
        const float bb = bo[n];
#pragma unroll
        for (int mi = 0; mi < 4; mi++) {
#pragma unroll
            for (int r = 0; r < 4; r++) {
                const int m = m0 + wm * 64 + mi * 16 + g * 4 + r;
                C[(size_t)m * 1024 + n] = acc[mi][ni][r] + bb;
            }
        }
    }
}

// ---------------------------------------------------------------------------
extern "C" void kernel_launch(void* const* d_in, const int* in_sizes, int n_in,
                              void* d_out, int out_size, void* d_ws, size_t ws_size,
                              hipStream_t stream)
{
    const float* x  = (const float*)d_in[0];
    const float* Wq = (const float*)d_in[1];
    const float* bq = (const float*)d_in[2];
    const float* Wk = (const float*)d_in[3];
    const float* bk = (const float*)d_in[4];
    const float* Wv = (const float*)d_in[5];
    const float* bv = (const float*)d_in[6];
    const float* Wo = (const float*)d_in[7];
    const float* bo = (const float*)d_in[8];
    float* out = (float*)d_out;

    bf16* qkv  = (bf16*)d_ws;                       // 3 x 8192x1024 bf16 = 48 MB
    bf16* attn = qkv + 3u * 8192u * 1024u;          // 8192x1024 bf16 = 16 MB

    qkv_gemm<<<dim3(8, 64, 3), dim3(256), 0, stream>>>(x, Wq, Wk, Wv, bq, bk, bv, qkv);
    attn_kernel<<<dim3(16, 64), dim3(256), 0, stream>>>(qkv, attn);
    out_gemm<<<dim3(8, 64), dim3(256), 0, stream>>>(attn, Wo, bo, out);
}

// Round 4
// 453.291 us; speedup vs baseline: 1.1643x; 1.1643x over previous
//
#include <hip/hip_runtime.h>

// MultiHeadSelfAttention: B=4, S=2048, E=1024, H=16, Dh=64.
// Stage 0: to_bf16   -> X (and W's if ws room) converted to bf16 once
// Stage 1: qkv_gemm  -> m97-style async-staged GEMM; q,k head-major, V transposed
// Stage 2: attn      -> swapped-QK^T flash attention (R1 structure) + XCD remap
// Stage 3: out_gemm  -> m97-style async-staged GEMM @ Wo^T + bo -> fp32

typedef __bf16 bf16;
typedef __attribute__((ext_vector_type(8))) short short8;
typedef __attribute__((ext_vector_type(4))) float floatx4;
typedef __attribute__((ext_vector_type(2))) unsigned int uintx2;

#define MFMA16(a, b, c) __builtin_amdgcn_mfma_f32_16x16x32_bf16((a), (b), (c), 0, 0, 0)

#define LDS_STRIDE 56   // fallback B staging: rows padded 32->56 elems, 16B-aligned
#define ATT_STRIDE 136  // P rows: 128 cols padded ->136 shorts (272 B): 16B-aligned

__device__ __forceinline__ float fast_exp2(float x) {
    float r;
    asm("v_exp_f32 %0, %1" : "=v"(r) : "v"(x));
    return r;
}
__device__ __forceinline__ unsigned int cvt_pk_bf16(float lo, float hi) {
    unsigned int r;
    asm("v_cvt_pk_bf16_f32 %0, %1, %2" : "=v"(r) : "v"(lo), "v"(hi));
    return r;
}

// async global->LDS, 16B per lane. lds base MUST be wave-uniform (SGPR);
// HW adds lane*16. Caller passes a base built from readfirstlane'd wave id.
__device__ __forceinline__ void async16(const bf16* __restrict__ g, short* l) {
    __builtin_amdgcn_global_load_lds((const __attribute__((address_space(1))) void*)g,
                                     (__attribute__((address_space(3))) void*)l, 16, 0, 0);
}

// 8 contiguous elements -> 8 bf16 (as short8 bit pattern)
__device__ __forceinline__ short8 frag8(const bf16* __restrict__ p) {
    return *(const short8*)p;
}
__device__ __forceinline__ short8 frag8(const float* __restrict__ p) {
    const floatx4 a = *(const floatx4*)p;
    const floatx4 b = *(const floatx4*)(p + 4);
    short8 r;
#pragma unroll
    for (int j = 0; j < 4; j++) {
        r[j]     = __builtin_bit_cast(short, (bf16)a[j]);
        r[4 + j] = __builtin_bit_cast(short, (bf16)b[j]);
    }
    return r;
}

// ---------------------------------------------------------------------------
// Stage 0: fp32 -> bf16 bulk convert. Each thread: 8 elems.
// ---------------------------------------------------------------------------
__global__ __launch_bounds__(256) void to_bf16(
    const float* __restrict__ in, bf16* __restrict__ out, int n8)
{
    const int i = blockIdx.x * 256 + threadIdx.x;
    if (i >= n8) return;
    const floatx4 a = *(const floatx4*)(in + (size_t)i * 8);
    const floatx4 b = *(const floatx4*)(in + (size_t)i * 8 + 4);
    short8 r;
#pragma unroll
    for (int j = 0; j < 4; j++) {
        r[j]     = __builtin_bit_cast(short, (bf16)a[j]);
        r[4 + j] = __builtin_bit_cast(short, (bf16)b[j]);
    }
    *(short8*)((short*)out + (size_t)i * 8) = r;
}

// ---------------------------------------------------------------------------
// m97-style 128x128 GEMM core. C[m][n] = sum_k A[m][k]*B[n][k], K=1024.
// A: bf16, staged via global_load_lds (linear LDS, XOR-swizzled source cols).
// B: bf16 -> same async path; float -> reg-staged with inline fp32->bf16 cvt.
// 256 threads = 4 waves (2x2 of 64x64), BK=32, single-buffered, 2 barriers.
// LDS layout: row m of the 128x32 tile at short-offset m*32; within each row
// quarter q holds source columns (q^(m&3))*8..+8 (involution swizzle).
// ---------------------------------------------------------------------------
template <typename TB>
__device__ __forceinline__ void gemm128_async(
    const bf16* __restrict__ A, const TB* __restrict__ B,
    int m0, int n0, short* As, short* Bs, floatx4 acc[4][4])
{
    constexpr bool BASYNC = (sizeof(TB) == 2);
    const int tid  = threadIdx.x;
    const int lane = tid & 63;
    const int w    = tid >> 6;
    // wave id as guaranteed-SGPR for the LDS staging base (wave-uniform req.)
    const int wu   = __builtin_amdgcn_readfirstlane(w);
    const int wm   = w >> 1, wn = w & 1;
    const int g    = lane >> 4, c = lane & 15;
    // async staging map: lane covers sub-row (lane>>2), 8-elem quarter (lane&3),
    // source quarter XOR-swizzled by row&3 so frag reads are ~2-way not 8-way.
    const int ar = lane >> 2;
    const int aq = ((lane & 3) ^ (ar & 3)) * 8;
    // fallback B staging map
    const int lrow = tid >> 2;
    const int lc8  = (tid & 3) * 8;

#pragma unroll
    for (int mi = 0; mi < 4; mi++)
#pragma unroll
        for (int ni = 0; ni < 4; ni++)
            acc[mi][ni] = (floatx4){0.f, 0.f, 0.f, 0.f};

    const int aswz = (g ^ (c & 3)) * 8;   // reader-side swizzled col offset

    for (int k0 = 0; k0 < 1024; k0 += 32) {
        async16(A + (size_t)(m0 + w * 32 + ar) * 1024 + k0 + aq,      As + wu * 1024);
        async16(A + (size_t)(m0 + w * 32 + 16 + ar) * 1024 + k0 + aq, As + wu * 1024 + 512);
        if constexpr (BASYNC) {
            const bf16* Bb = (const bf16*)B;
            async16(Bb + (size_t)(n0 + w * 32 + ar) * 1024 + k0 + aq,      Bs + wu * 1024);
            async16(Bb + (size_t)(n0 + w * 32 + 16 + ar) * 1024 + k0 + aq, Bs + wu * 1024 + 512);
        } else {
            *(short8*)(Bs + lrow * LDS_STRIDE + lc8) =
                frag8(B + (size_t)(n0 + lrow) * 1024 + k0 + lc8);
            *(short8*)(Bs + (lrow + 64) * LDS_STRIDE + lc8) =
                frag8(B + (size_t)(n0 + lrow + 64) * 1024 + k0 + lc8);
        }
        __syncthreads();   // drains vmcnt (async loads) + lgkm

        short8 af[4], bfr[4];
#pragma unroll
        for (int mi = 0; mi < 4; mi++)
            af[mi] = *(const short8*)(As + (wm * 64 + mi * 16 + c) * 32 + aswz);
#pragma unroll
        for (int ni = 0; ni < 4; ni++) {
            if constexpr (BASYNC)
                bfr[ni] = *(const short8*)(Bs + (wn * 64 + ni * 16 + c) * 32 + aswz);
            else
                bfr[ni] = *(const short8*)(Bs + (wn * 64 + ni * 16 + c) * LDS_STRIDE + g * 8);
        }
#pragma unroll
        for (int mi = 0; mi < 4; mi++)
#pragma unroll
            for (int ni = 0; ni < 4; ni++)
                acc[mi][ni] = MFMA16(af[mi], bfr[ni], acc[mi][ni]);
        __syncthreads();
    }
}

// ---------------------------------------------------------------------------
// Stage 1: q/k/v = x @ W{q,k,v}^T + b, scattered to head-major bf16.
// q,k: [bh][s][64].  v: TRANSPOSED [bh][d][2048].
// grid (8, 64, 3), block 256
// ---------------------------------------------------------------------------
template <typename TB>
__global__ __launch_bounds__(256) void qkv_gemm(
    const bf16* __restrict__ Xb,
    const TB* __restrict__ Wq, const TB* __restrict__ Wk, const TB* __restrict__ Wv,
    const float* __restrict__ bq, const float* __restrict__ bk, const float* __restrict__ bv,
    bf16* __restrict__ qkv)
{
    __shared__ __align__(16) short As[128 * 32];
    __shared__ __align__(16) short Bs[(sizeof(TB) == 2) ? 128 * 32 : 128 * LDS_STRIDE];

    const int z = blockIdx.z;
    const TB* W       = (z == 0) ? Wq : (z == 1) ? Wk : Wv;
    const float* bias = (z == 0) ? bq : (z == 1) ? bk : bv;
    bf16* outz = qkv + (size_t)z * (8192u * 1024u);

    const int m0 = blockIdx.y * 128;
    const int n0 = blockIdx.x * 128;

    floatx4 acc[4][4];
    gemm128_async(Xb, W, m0, n0, As, Bs, acc);

    const int lane = threadIdx.x & 63;
    const int w = threadIdx.x >> 6;
    const int wm = w >> 1, wn = w & 1;
    const int g = lane >> 4, c = lane & 15;

#pragma unroll
    for (int ni = 0; ni < 4; ni++) {
        const int n = n0 + wn * 64 + ni * 16 + c;
        const float bb = bias[n];
        const int h = n >> 6, d = n & 63;
#pragma unroll
        for (int mi = 0; mi < 4; mi++) {
#pragma unroll
            for (int r = 0; r < 4; r++) {
                const int m = m0 + wm * 64 + mi * 16 + g * 4 + r;
                const int b = m >> 11, s = m & 2047;
                const size_t idx = (z == 2)
                    ? ((((size_t)((b << 4) | h)) * 64 + d) * 2048 + s)    // V^T
                    : ((((size_t)((b << 4) | h)) * 2048 + s) * 64 + d);   // Q,K
                outz[idx] = (bf16)(acc[mi][ni][r] + bb);
            }
        }
    }
}

// ---------------------------------------------------------------------------
// Stage 2: flash attention, swapped QK^T, barrier-free (R1 structure).
// grid (16, 64), block 256, XCD-sliced remap: each XCD owns 8 whole heads.
// ---------------------------------------------------------------------------
__global__ __launch_bounds__(256) void attn_kernel(
    const bf16* __restrict__ qkv, bf16* __restrict__ attn_out)
{
    __shared__ __align__(16) short Pl[4 * 32 * ATT_STRIDE];   // 34.8 KB

    const int linear = blockIdx.y * gridDim.x + blockIdx.x;
    const int slot = linear >> 3;
    const int bh = (linear & 7) * 8 + (slot >> 4);            // 0..63
    const int q0 = (slot & 15) * 128;

    const size_t HSTRIDE = 2048u * 64u;
    const bf16* __restrict__ Q  = qkv + (size_t)bh * HSTRIDE;
    const bf16* __restrict__ Kp = qkv + 8192u * 1024u + (size_t)bh * HSTRIDE;
    const bf16* __restrict__ Vt = qkv + 2u * 8192u * 1024u + (size_t)bh * HSTRIDE; // [64][2048]

    const int tid  = threadIdx.x;
    const int lane = tid & 63;
    const int w    = tid >> 6;
    const int g    = lane >> 4, c = lane & 15;
    short* __restrict__ Pw = Pl + w * (32 * ATT_STRIDE);

    const float C2 = 0.04508422002778f;  // (1/sqrt(1024)) * log2(e)

    short8 qf[2][2];
#pragma unroll
    for (int qb = 0; qb < 2; qb++)
#pragma unroll
        for (int ks = 0; ks < 2; ks++)
            qf[qb][ks] = *(const short8*)(Q + (size_t)(q0 + w * 32 + qb * 16 + c) * 64
                                            + ks * 32 + g * 8);

    floatx4 o[2][4];
#pragma unroll
    for (int mi = 0; mi < 2; mi++)
#pragma unroll
        for (int di = 0; di < 4; di++)
            o[mi][di] = (floatx4){0.f, 0.f, 0.f, 0.f};
    float m_run[2] = {-1e30f, -1e30f};
    float l_run[2] = {0.f, 0.f};

    for (int kb = 0; kb < 16; kb++) {
        const int k0 = kb * 128;

        // S^T = K Q^T: rows = keys, cols = queries (swapped operands)
        floatx4 sAcc[2][8];
#pragma unroll
        for (int qb = 0; qb < 2; qb++)
#pragma unroll
            for (int ni = 0; ni < 8; ni++)
                sAcc[qb][ni] = (floatx4){0.f, 0.f, 0.f, 0.f};
#pragma unroll
        for (int ks = 0; ks < 2; ks++) {
            short8 kf[8];
#pragma unroll
            for (int ni = 0; ni < 8; ni++)
                kf[ni] = *(const short8*)(Kp + (size_t)(k0 + ni * 16 + c) * 64
                                             + ks * 32 + g * 8);
#pragma unroll
            for (int qb = 0; qb < 2; qb++)
#pragma unroll
                for (int ni = 0; ni < 8; ni++)
                    sAcc[qb][ni] = MFMA16(kf[ni], qf[qb][ks], sAcc[qb][ni]);
        }

        // online softmax: lane (g,c) holds 32 scores of query qb*16+c
        float alpha[2];
#pragma unroll
        for (int qb = 0; qb < 2; qb++) {
            floatx4 mv = sAcc[qb][0];
#pragma unroll
            for (int ni = 1; ni < 8; ni++)
#pragma unroll
                for (int r = 0; r < 4; r++) mv[r] = fmaxf(mv[r], sAcc[qb][ni][r]);
            float mx = fmaxf(fmaxf(mv[0], mv[1]), fmaxf(mv[2], mv[3]));
            mx = fmaxf(mx, __shfl_xor(mx, 16));
            mx = fmaxf(mx, __shfl_xor(mx, 32));
            const float mnew = fmaxf(m_run[qb], mx * C2);
            alpha[qb] = fast_exp2(m_run[qb] - mnew);
            m_run[qb] = mnew;

            floatx4 sv = {0.f, 0.f, 0.f, 0.f};
#pragma unroll
            for (int ni = 0; ni < 8; ni++)
#pragma unroll
                for (int r = 0; r < 4; r++) {
                    const float p = fast_exp2(fmaf(sAcc[qb][ni][r], C2, -mnew));
                    sAcc[qb][ni][r] = p;
                    sv[r] += p;
                }
            float sum = (sv[0] + sv[1]) + (sv[2] + sv[3]);
            sum += __shfl_xor(sum, 16);
            sum += __shfl_xor(sum, 32);
            l_run[qb] = l_run[qb] * alpha[qb] + sum;

#pragma unroll
            for (int ni = 0; ni < 8; ni++) {
                uintx2 pk;
                pk[0] = cvt_pk_bf16(sAcc[qb][ni][0], sAcc[qb][ni][1]);
                pk[1] = cvt_pk_bf16(sAcc[qb][ni][2], sAcc[qb][ni][3]);
                *(uintx2*)(Pw + (qb * 16 + c) * ATT_STRIDE + ni * 16 + g * 4) = pk;
            }
        }

        // rescale O by per-row alpha (row 4g+r's stats live at lane with c == 4g+r)
#pragma unroll
        for (int mi = 0; mi < 2; mi++)
#pragma unroll
            for (int r = 0; r < 4; r++) {
                const int src = (lane & 48) | (g * 4 + r);
                const float a = __shfl(alpha[mi], src);
#pragma unroll
                for (int di = 0; di < 4; di++) o[mi][di][r] *= a;
            }

        // O += P V   (A = P from wave-private LDS, B = V^T rows from global/L2)
#pragma unroll
        for (int ks2 = 0; ks2 < 4; ks2++) {
            short8 vf[4], pf[2];
#pragma unroll
            for (int di = 0; di < 4; di++)
                vf[di] = *(const short8*)(Vt + (size_t)(di * 16 + c) * 2048
                                             + k0 + ks2 * 32 + g * 8);
#pragma unroll
            for (int mi = 0; mi < 2; mi++)
                pf[mi] = *(const short8*)(Pw + (mi * 16 + c) * ATT_STRIDE + ks2 * 32 + g * 8);
#pragma unroll
            for (int mi = 0; mi < 2; mi++)
#pragma unroll
                for (int di = 0; di < 4; di++)
                    o[mi][di] = MFMA16(pf[mi], vf[di], o[mi][di]);
        }
    }

    // epilogue: O /= l (redistribute l to O's row layout), write bf16
    const int b = bh >> 4, h = bh & 15;
#pragma unroll
    for (int mi = 0; mi < 2; mi++) {
#pragma unroll
        for (int r = 0; r < 4; r++) {
            const int src = (lane & 48) | (g * 4 + r);
            const float linv = 1.0f / __shfl(l_run[mi], src);
            const int srow = q0 + w * 32 + mi * 16 + g * 4 + r;
#pragma unroll
            for (int di = 0; di < 4; di++) {
                attn_out[((size_t)(b * 2048 + srow)) * 1024 + h * 64 + di * 16 + c] =
                    (bf16)(o[mi][di][r] * linv);
            }
        }
    }
}

// ---------------------------------------------------------------------------
// Stage 3: out = attn @ Wo^T + bo -> fp32. grid (8, 64).
// ---------------------------------------------------------------------------
template <typename TB>
__global__ __launch_bounds__(256) void out_gemm(
    const bf16* __restrict__ A, const TB* __restrict__ Wo,
    const float* __restrict__ bo, float* __restrict__ C)
{
    __shared__ __align__(16) short As[128 * 32];
    __shared__ __align__(16) short Bs[(sizeof(TB) == 2) ? 128 * 32 : 128 * LDS_STRIDE];

    const int m0 = blockIdx.y * 128;
    const int n0 = blockIdx.x * 128;

    floatx4 acc[4][4];
    gemm128_async(A, Wo, m0, n0, As, Bs, acc);

    const int lane = threadIdx.x & 63;
    const int w = threadIdx.x >> 6;
    const int wm = w >> 1, wn = w & 1;
    const int g = lane >> 4, c = lane & 15;

#pragma unroll
    for (int ni = 0; ni < 4; ni++) {
        const int n = n0 + wn * 64 + ni * 16 + c;
        const float bb = bo[n];
#pragma unroll
        for (int mi = 0; mi < 4; mi++) {
#pragma unroll
            for (int r = 0; r < 4; r++) {
                const int m = m0 + wm * 64 + mi * 16 + g * 4 + r;
                C[(size_t)m * 1024 + n] = acc[mi][ni][r] + bb;
            }
        }
    }
}

// ---------------------------------------------------------------------------
extern "C" void kernel_launch(void* const* d_in, const int* in_sizes, int n_in,
                              void* d_out, int out_size, void* d_ws, size_t ws_size,
                              hipStream_t stream)
{
    const float* x  = (const float*)d_in[0];
    const float* Wq = (const float*)d_in[1];
    const float* bq = (const float*)d_in[2];
    const float* Wk = (const float*)d_in[3];
    const float* bk = (const float*)d_in[4];
    const float* Wv = (const float*)d_in[5];
    const float* bv = (const float*)d_in[6];
    const float* Wo = (const float*)d_in[7];
    const float* bo = (const float*)d_in[8];
    float* out = (float*)d_out;

    bf16* qkv  = (bf16*)d_ws;                       // 3 x 8192x1024 bf16 = 48 MB
    bf16* attn = qkv + 3u * 8192u * 1024u;          // 8192x1024 bf16 = 16 MB
    bf16* xb   = attn;   // X-bf16 aliases attn region (dead before attn written)

    const size_t base = 64u * 1024u * 1024u;
    const bool haveW = ws_size >= base + 8u * 1024u * 1024u;
    bf16* wb = (bf16*)((char*)d_ws + base);         // 4 x 1024x1024 bf16 = 8 MB

    to_bf16<<<dim3(4096), dim3(256), 0, stream>>>(x, xb, 1048576);   // 8.4M elems

    if (haveW) {
        to_bf16<<<dim3(512), dim3(256), 0, stream>>>(Wq, wb + 0u * 1048576u, 131072);
        to_bf16<<<dim3(512), dim3(256), 0, stream>>>(Wk, wb + 1u * 1048576u, 131072);
        to_bf16<<<dim3(512), dim3(256), 0, stream>>>(Wv, wb + 2u * 1048576u, 131072);
        to_bf16<<<dim3(512), dim3(256), 0, stream>>>(Wo, wb + 3u * 1048576u, 131072);
        qkv_gemm<bf16><<<dim3(8, 64, 3), dim3(256), 0, stream>>>(
            xb, wb, wb + 1048576u, wb + 2u * 1048576u, bq, bk, bv, qkv);
    } else {
        qkv_gemm<float><<<dim3(8, 64, 3), dim3(256), 0, stream>>>(
            xb, Wq, Wk, Wv, bq, bk, bv, qkv);
    }

    attn_kernel<<<dim3(16, 64), dim3(256), 0, stream>>>(qkv, attn);

    if (haveW) {
        out_gemm<bf16><<<dim3(8, 64), dim3(256), 0, stream>>>(
            attn, wb + 3u * 1048576u, bo, out);
    } else {
        out_gemm<float><<<dim3(8, 64), dim3(256), 0, stream>>>(attn, Wo, bo, out);
    }
}

// Round 5
// 416.650 us; speedup vs baseline: 1.2666x; 1.0879x over previous
//
#include <hip/hip_runtime.h>

// MultiHeadSelfAttention: B=4, S=2048, E=1024, H=16, Dh=64.
// Stage 0: to_bf16   -> X (and W's if ws room) converted to bf16 once
// Stage 1: qkv_gemm  -> m97-style async-staged GEMM; q,k head-major, V transposed
// Stage 2: attn      -> LDS-staged K/V (m97 pattern), swapped QK^T, shuffle-P
// Stage 3: out_gemm  -> m97-style async-staged GEMM @ Wo^T + bo -> fp32

typedef __bf16 bf16;
typedef __attribute__((ext_vector_type(8))) short short8;
typedef __attribute__((ext_vector_type(4))) float floatx4;
typedef __attribute__((ext_vector_type(4))) unsigned int uintx4;

#define MFMA16(a, b, c) __builtin_amdgcn_mfma_f32_16x16x32_bf16((a), (b), (c), 0, 0, 0)

#define LDS_STRIDE 56   // fallback B staging: rows padded 32->56 elems, 16B-aligned

__device__ __forceinline__ float fast_exp2(float x) {
    float r;
    asm("v_exp_f32 %0, %1" : "=v"(r) : "v"(x));
    return r;
}
__device__ __forceinline__ unsigned int cvt_pk_bf16(float lo, float hi) {
    unsigned int r;
    asm("v_cvt_pk_bf16_f32 %0, %1, %2" : "=v"(r) : "v"(lo), "v"(hi));
    return r;
}

// async global->LDS, 16B per lane. lds base MUST be wave-uniform (SGPR);
// HW adds lane*16. Caller passes a base built from readfirstlane'd wave id.
__device__ __forceinline__ void async16(const bf16* __restrict__ g, short* l) {
    __builtin_amdgcn_global_load_lds((const __attribute__((address_space(1))) void*)g,
                                     (__attribute__((address_space(3))) void*)l, 16, 0, 0);
}

// 8 contiguous elements -> 8 bf16 (as short8 bit pattern)
__device__ __forceinline__ short8 frag8(const bf16* __restrict__ p) {
    return *(const short8*)p;
}
__device__ __forceinline__ short8 frag8(const float* __restrict__ p) {
    const floatx4 a = *(const floatx4*)p;
    const floatx4 b = *(const floatx4*)(p + 4);
    short8 r;
#pragma unroll
    for (int j = 0; j < 4; j++) {
        r[j]     = __builtin_bit_cast(short, (bf16)a[j]);
        r[4 + j] = __builtin_bit_cast(short, (bf16)b[j]);
    }
    return r;
}

// ---------------------------------------------------------------------------
// Stage 0: fp32 -> bf16 bulk convert. Each thread: 8 elems.
// ---------------------------------------------------------------------------
__global__ __launch_bounds__(256) void to_bf16(
    const float* __restrict__ in, bf16* __restrict__ out, int n8)
{
    const int i = blockIdx.x * 256 + threadIdx.x;
    if (i >= n8) return;
    const floatx4 a = *(const floatx4*)(in + (size_t)i * 8);
    const floatx4 b = *(const floatx4*)(in + (size_t)i * 8 + 4);
    short8 r;
#pragma unroll
    for (int j = 0; j < 4; j++) {
        r[j]     = __builtin_bit_cast(short, (bf16)a[j]);
        r[4 + j] = __builtin_bit_cast(short, (bf16)b[j]);
    }
    *(short8*)((short*)out + (size_t)i * 8) = r;
}

// ---------------------------------------------------------------------------
// m97-style 128x128 GEMM core (unchanged from R4 — verified).
// ---------------------------------------------------------------------------
template <typename TB>
__device__ __forceinline__ void gemm128_async(
    const bf16* __restrict__ A, const TB* __restrict__ B,
    int m0, int n0, short* As, short* Bs, floatx4 acc[4][4])
{
    constexpr bool BASYNC = (sizeof(TB) == 2);
    const int tid  = threadIdx.x;
    const int lane = tid & 63;
    const int w    = tid >> 6;
    const int wu   = __builtin_amdgcn_readfirstlane(w);
    const int wm   = w >> 1, wn = w & 1;
    const int g    = lane >> 4, c = lane & 15;
    const int ar = lane >> 2;
    const int aq = ((lane & 3) ^ (ar & 3)) * 8;
    const int lrow = tid >> 2;
    const int lc8  = (tid & 3) * 8;

#pragma unroll
    for (int mi = 0; mi < 4; mi++)
#pragma unroll
        for (int ni = 0; ni < 4; ni++)
            acc[mi][ni] = (floatx4){0.f, 0.f, 0.f, 0.f};

    const int aswz = (g ^ (c & 3)) * 8;

    for (int k0 = 0; k0 < 1024; k0 += 32) {
        async16(A + (size_t)(m0 + w * 32 + ar) * 1024 + k0 + aq,      As + wu * 1024);
        async16(A + (size_t)(m0 + w * 32 + 16 + ar) * 1024 + k0 + aq, As + wu * 1024 + 512);
        if constexpr (BASYNC) {
            const bf16* Bb = (const bf16*)B;
            async16(Bb + (size_t)(n0 + w * 32 + ar) * 1024 + k0 + aq,      Bs + wu * 1024);
            async16(Bb + (size_t)(n0 + w * 32 + 16 + ar) * 1024 + k0 + aq, Bs + wu * 1024 + 512);
        } else {
            *(short8*)(Bs + lrow * LDS_STRIDE + lc8) =
                frag8(B + (size_t)(n0 + lrow) * 1024 + k0 + lc8);
            *(short8*)(Bs + (lrow + 64) * LDS_STRIDE + lc8) =
                frag8(B + (size_t)(n0 + lrow + 64) * 1024 + k0 + lc8);
        }
        __syncthreads();

        short8 af[4], bfr[4];
#pragma unroll
        for (int mi = 0; mi < 4; mi++)
            af[mi] = *(const short8*)(As + (wm * 64 + mi * 16 + c) * 32 + aswz);
#pragma unroll
        for (int ni = 0; ni < 4; ni++) {
            if constexpr (BASYNC)
                bfr[ni] = *(const short8*)(Bs + (wn * 64 + ni * 16 + c) * 32 + aswz);
            else
                bfr[ni] = *(const short8*)(Bs + (wn * 64 + ni * 16 + c) * LDS_STRIDE + g * 8);
        }
#pragma unroll
        for (int mi = 0; mi < 4; mi++)
#pragma unroll
            for (int ni = 0; ni < 4; ni++)
                acc[mi][ni] = MFMA16(af[mi], bfr[ni], acc[mi][ni]);
        __syncthreads();
    }
}

// ---------------------------------------------------------------------------
// Stage 1: q/k/v = x @ W{q,k,v}^T + b, scattered to head-major bf16.
// q,k: [bh][s][64].  v: TRANSPOSED [bh][d][2048].
// ---------------------------------------------------------------------------
template <typename TB>
__global__ __launch_bounds__(256) void qkv_gemm(
    const bf16* __restrict__ Xb,
    const TB* __restrict__ Wq, const TB* __restrict__ Wk, const TB* __restrict__ Wv,
    const float* __restrict__ bq, const float* __restrict__ bk, const float* __restrict__ bv,
    bf16* __restrict__ qkv)
{
    __shared__ __align__(16) short As[128 * 32];
    __shared__ __align__(16) short Bs[(sizeof(TB) == 2) ? 128 * 32 : 128 * LDS_STRIDE];

    const int z = blockIdx.z;
    const TB* W       = (z == 0) ? Wq : (z == 1) ? Wk : Wv;
    const float* bias = (z == 0) ? bq : (z == 1) ? bk : bv;
    bf16* outz = qkv + (size_t)z * (8192u * 1024u);

    const int m0 = blockIdx.y * 128;
    const int n0 = blockIdx.x * 128;

    floatx4 acc[4][4];
    gemm128_async(Xb, W, m0, n0, As, Bs, acc);

    const int lane = threadIdx.x & 63;
    const int w = threadIdx.x >> 6;
    const int wm = w >> 1, wn = w & 1;
    const int g = lane >> 4, c = lane & 15;

#pragma unroll
    for (int ni = 0; ni < 4; ni++) {
        const int n = n0 + wn * 64 + ni * 16 + c;
        const float bb = bias[n];
        const int h = n >> 6, d = n & 63;
#pragma unroll
        for (int mi = 0; mi < 4; mi++) {
#pragma unroll
            for (int r = 0; r < 4; r++) {
                const int m = m0 + wm * 64 + mi * 16 + g * 4 + r;
                const int b = m >> 11, s = m & 2047;
                const size_t idx = (z == 2)
                    ? ((((size_t)((b << 4) | h)) * 64 + d) * 2048 + s)    // V^T
                    : ((((size_t)((b << 4) | h)) * 2048 + s) * 64 + d);   // Q,K
                outz[idx] = (bf16)(acc[mi][ni][r] + bb);
            }
        }
    }
}

// ---------------------------------------------------------------------------
// Stage 2: flash attention. grid (16,64), block 256 (4 waves), XCD-sliced.
// Per iteration: K-block (128x64) and V^T-block (64x128) cooperatively staged
// into LDS via swizzled global_load_lds; swapped QK^T; in-register softmax;
// P redistributed to PV A-fragments via __shfl (no P LDS); PV from LDS V.
// LDS = 32 KB -> 4 blocks/CU resident.
// ---------------------------------------------------------------------------
__global__ __launch_bounds__(256) void attn_kernel(
    const bf16* __restrict__ qkv, bf16* __restrict__ attn_out)
{
    __shared__ __align__(16) short Ks[128 * 64];   // [key][d], chunk^=(row&7)
    __shared__ __align__(16) short Vs[64 * 128];   // [d][key], chunk^=(row&15)

    const int linear = blockIdx.y * gridDim.x + blockIdx.x;
    const int slot = linear >> 3;
    const int bh = (linear & 7) * 8 + (slot >> 4);            // 0..63
    const int q0 = (slot & 15) * 128;

    const size_t HSTRIDE = 2048u * 64u;
    const bf16* __restrict__ Q  = qkv + (size_t)bh * HSTRIDE;
    const bf16* __restrict__ Kp = qkv + 8192u * 1024u + (size_t)bh * HSTRIDE;
    const bf16* __restrict__ Vt = qkv + 2u * 8192u * 1024u + (size_t)bh * HSTRIDE; // [64][2048]

    const int tid  = threadIdx.x;
    const int lane = tid & 63;
    const int w    = tid >> 6;
    const int wu   = __builtin_amdgcn_readfirstlane(w);
    const int g    = lane >> 4, c = lane & 15;

    const float C2 = 0.04508422002778f;  // (1/sqrt(1024)) * log2(e)

    // Q fragments resident in regs (A-layout; used as B operand in swapped QK^T)
    short8 qf[2][2];
#pragma unroll
    for (int qb = 0; qb < 2; qb++)
#pragma unroll
        for (int ks = 0; ks < 2; ks++)
            qf[qb][ks] = *(const short8*)(Q + (size_t)(q0 + w * 32 + qb * 16 + c) * 64
                                            + ks * 32 + g * 8);

    floatx4 o[2][4];
#pragma unroll
    for (int mi = 0; mi < 2; mi++)
#pragma unroll
        for (int di = 0; di < 4; di++)
            o[mi][di] = (floatx4){0.f, 0.f, 0.f, 0.f};
    float m_run[2] = {-1e30f, -1e30f};
    float l_run[2] = {0.f, 0.f};

    // staging source maps (per-lane, loop-invariant)
    const int krow_off = lane >> 3;                 // K: 8 rows per async16
    const int kchunk   = (lane & 7) ^ (lane >> 3);  // source chunk (involution)
    const int vrow_off = lane >> 4;                 // V: 4 rows per async16

    // shuffle-P source lanes
    const int s0l = 32 * (g & 1) + c;
    const int s1l = s0l + 16;
    const bool gh = ((g >> 1) & 1) != 0;

    for (int kb = 0; kb < 16; kb++) {
        const int k0 = kb * 128;

        __syncthreads();   // all waves done with previous K/V tiles
        // stage K-block: wave w covers rows w*32..w*32+31 (4 async16 x 8 rows)
#pragma unroll
        for (int s = 0; s < 4; s++) {
            const int row = w * 32 + s * 8 + krow_off;
            async16(Kp + (size_t)(k0 + row) * 64 + kchunk * 8,
                    Ks + (wu * 32 + s * 8) * 64);
        }
        // stage V^T-block: wave w covers d-rows w*16..w*16+15 (4 async16 x 4 rows)
#pragma unroll
        for (int s = 0; s < 4; s++) {
            const int row = w * 16 + s * 4 + vrow_off;
            const int vchunk = (lane & 15) ^ (row & 15);
            async16(Vt + (size_t)row * 2048 + k0 + vchunk * 8,
                    Vs + (wu * 16 + s * 4) * 128);
        }
        __syncthreads();   // drains vmcnt -> tiles visible

        // S^T = K Q^T from LDS: lane (g,c) holds S[key=16ni+4g+r][q=qb*16+c]
        floatx4 sAcc[2][8];
#pragma unroll
        for (int qb = 0; qb < 2; qb++)
#pragma unroll
            for (int ni = 0; ni < 8; ni++)
                sAcc[qb][ni] = (floatx4){0.f, 0.f, 0.f, 0.f};
#pragma unroll
        for (int ks = 0; ks < 2; ks++)
#pragma unroll
            for (int ni = 0; ni < 8; ni++) {
                const short8 kf = *(const short8*)(
                    Ks + (16 * ni + c) * 64 + (((ks * 4 + g) ^ (c & 7)) * 8));
                sAcc[0][ni] = MFMA16(kf, qf[0][ks], sAcc[0][ni]);
                sAcc[1][ni] = MFMA16(kf, qf[1][ks], sAcc[1][ni]);
            }

        // online softmax + bf16 pack (lo/hi pairs, kept in regs)
        float alpha[2];
        unsigned int lo[2][8], hi[2][8];
#pragma unroll
        for (int qb = 0; qb < 2; qb++) {
            floatx4 mv = sAcc[qb][0];
#pragma unroll
            for (int ni = 1; ni < 8; ni++)
#pragma unroll
                for (int r = 0; r < 4; r++) mv[r] = fmaxf(mv[r], sAcc[qb][ni][r]);
            float mx = fmaxf(fmaxf(mv[0], mv[1]), fmaxf(mv[2], mv[3]));
            mx = fmaxf(mx, __shfl_xor(mx, 16));
            mx = fmaxf(mx, __shfl_xor(mx, 32));
            const float mnew = fmaxf(m_run[qb], mx * C2);
            alpha[qb] = fast_exp2(m_run[qb] - mnew);
            m_run[qb] = mnew;

            floatx4 sv = {0.f, 0.f, 0.f, 0.f};
#pragma unroll
            for (int ni = 0; ni < 8; ni++) {
#pragma unroll
                for (int r = 0; r < 4; r++) {
                    const float p = fast_exp2(fmaf(sAcc[qb][ni][r], C2, -mnew));
                    sAcc[qb][ni][r] = p;
                    sv[r] += p;
                }
                lo[qb][ni] = cvt_pk_bf16(sAcc[qb][ni][0], sAcc[qb][ni][1]);
                hi[qb][ni] = cvt_pk_bf16(sAcc[qb][ni][2], sAcc[qb][ni][3]);
            }
            float sum = (sv[0] + sv[1]) + (sv[2] + sv[3]);
            sum += __shfl_xor(sum, 16);
            sum += __shfl_xor(sum, 32);
            l_run[qb] = l_run[qb] * alpha[qb] + sum;
        }

        // rescale O by per-row alpha (row 4g+r's stats live at lane with c == 4g+r)
#pragma unroll
        for (int mi = 0; mi < 2; mi++)
#pragma unroll
            for (int r = 0; r < 4; r++) {
                const int src = (lane & 48) | (g * 4 + r);
                const float a = __shfl(alpha[mi], src);
#pragma unroll
                for (int di = 0; di < 4; di++) o[mi][di][r] *= a;
            }

        // O += P V.  pf[mi] built by shuffle: lane (g,c) needs
        // P[q=mi*16+c][key=32ks2+8g+j] = word w from lane 32(g&1)+16(w>>1)+c,
        // value {lo,hi}[2ks2+(g>>1)].
#pragma unroll
        for (int ks2 = 0; ks2 < 4; ks2++) {
            short8 pf[2];
#pragma unroll
            for (int mi = 0; mi < 2; mi++) {
                const unsigned int w0a = __shfl(lo[mi][2 * ks2],     s0l);
                const unsigned int w0b = __shfl(lo[mi][2 * ks2 + 1], s0l);
                const unsigned int w1a = __shfl(hi[mi][2 * ks2],     s0l);
                const unsigned int w1b = __shfl(hi[mi][2 * ks2 + 1], s0l);
                const unsigned int w2a = __shfl(lo[mi][2 * ks2],     s1l);
                const unsigned int w2b = __shfl(lo[mi][2 * ks2 + 1], s1l);
                const unsigned int w3a = __shfl(hi[mi][2 * ks2],     s1l);
                const unsigned int w3b = __shfl(hi[mi][2 * ks2 + 1], s1l);
                uintx4 pw;
                pw[0] = gh ? w0b : w0a;
                pw[1] = gh ? w1b : w1a;
                pw[2] = gh ? w2b : w2a;
                pw[3] = gh ? w3b : w3a;
                pf[mi] = __builtin_bit_cast(short8, pw);
            }
#pragma unroll
            for (int di = 0; di < 4; di++) {
                const short8 vf = *(const short8*)(
                    Vs + (di * 16 + c) * 128 + (((ks2 * 4 + g) ^ c) * 8));
                o[0][di] = MFMA16(pf[0], vf, o[0][di]);
                o[1][di] = MFMA16(pf[1], vf, o[1][di]);
            }
        }
    }

    // epilogue: O /= l (redistribute l to O's row layout), write bf16
    const int b = bh >> 4, h = bh & 15;
#pragma unroll
    for (int mi = 0; mi < 2; mi++) {
#pragma unroll
        for (int r = 0; r < 4; r++) {
            const int src = (lane & 48) | (g * 4 + r);
            const float linv = 1.0f / __shfl(l_run[mi], src);
            const int srow = q0 + w * 32 + mi * 16 + g * 4 + r;
#pragma unroll
            for (int di = 0; di < 4; di++) {
                attn_out[((size_t)(b * 2048 + srow)) * 1024 + h * 64 + di * 16 + c] =
                    (bf16)(o[mi][di][r] * linv);
            }
        }
    }
}

// ---------------------------------------------------------------------------
// Stage 3: out = attn @ Wo^T + bo -> fp32. grid (8, 64).
// ---------------------------------------------------------------------------
template <typename TB>
__global__ __launch_bounds__(256) void out_gemm(
    const bf16* __restrict__ A, const TB* __restrict__ Wo,
    const float* __restrict__ bo, float* __restrict__ C)
{
    __shared__ __align__(16) short As[128 * 32];
    __shared__ __align__(16) short Bs[(sizeof(TB) == 2) ? 128 * 32 : 128 * LDS_STRIDE];

    const int m0 = blockIdx.y * 128;
    const int n0 = blockIdx.x * 128;

    floatx4 acc[4][4];
    gemm128_async(A, Wo, m0, n0, As, Bs, acc);

    const int lane = threadIdx.x & 63;
    const int w = threadIdx.x >> 6;
    const int wm = w >> 1, wn = w & 1;
    const int g = lane >> 4, c = lane & 15;

#pragma unroll
    for (int ni = 0; ni < 4; ni++) {
        const int n = n0 + wn * 64 + ni * 16 + c;
        const float bb = bo[n];
#pragma unroll
        for (int mi = 0; mi < 4; mi++) {
#pragma unroll
            for (int r = 0; r < 4; r++) {
                const int m = m0 + wm * 64 + mi * 16 + g * 4 + r;
                C[(size_t)m * 1024 + n] = acc[mi][ni][r] + bb;
            }
        }
    }
}

// ---------------------------------------------------------------------------
extern "C" void kernel_launch(void* const* d_in, const int* in_sizes, int n_in,
                              void* d_out, int out_size, void* d_ws, size_t ws_size,
                              hipStream_t stream)
{
    const float* x  = (const float*)d_in[0];
    const float* Wq = (const float*)d_in[1];
    const float* bq = (const float*)d_in[2];
    const float* Wk = (const float*)d_in[3];
    const float* bk = (const float*)d_in[4];
    const float* Wv = (const float*)d_in[5];
    const float* bv = (const float*)d_in[6];
    const float* Wo = (const float*)d_in[7];
    const float* bo = (const float*)d_in[8];
    float* out = (float*)d_out;

    bf16* qkv  = (bf16*)d_ws;                       // 3 x 8192x1024 bf16 = 48 MB
    bf16* attn = qkv + 3u * 8192u * 1024u;          // 8192x1024 bf16 = 16 MB
    bf16* xb   = attn;   // X-bf16 aliases attn region (dead before attn written)

    const size_t base = 64u * 1024u * 1024u;
    const bool haveW = ws_size >= base + 8u * 1024u * 1024u;
    bf16* wb = (bf16*)((char*)d_ws + base);         // 4 x 1024x1024 bf16 = 8 MB

    to_bf16<<<dim3(4096), dim3(256), 0, stream>>>(x, xb, 1048576);

    if (haveW) {
        to_bf16<<<dim3(512), dim3(256), 0, stream>>>(Wq, wb + 0u * 1048576u, 131072);
        to_bf16<<<dim3(512), dim3(256), 0, stream>>>(Wk, wb + 1u * 1048576u, 131072);
        to_bf16<<<dim3(512), dim3(256), 0, stream>>>(Wv, wb + 2u * 1048576u, 131072);
        to_bf16<<<dim3(512), dim3(256), 0, stream>>>(Wo, wb + 3u * 1048576u, 131072);
        qkv_gemm<bf16><<<dim3(8, 64, 3), dim3(256), 0, stream>>>(
            xb, wb, wb + 1048576u, wb + 2u * 1048576u, bq, bk, bv, qkv);
    } else {
        qkv_gemm<float><<<dim3(8, 64, 3), dim3(256), 0, stream>>>(
            xb, Wq, Wk, Wv, bq, bk, bv, qkv);
    }

    attn_kernel<<<dim3(16, 64), dim3(256), 0, stream>>>(qkv, attn);

    if (haveW) {
        out_gemm<bf16><<<dim3(8, 64), dim3(256), 0, stream>>>(
            attn, wb + 3u * 1048576u, bo, out);
    } else {
        out_gemm<float><<<dim3(8, 64), dim3(256), 0, stream>>>(attn, Wo, bo, out);
    }
}

// Round 6
// 339.704 us; speedup vs baseline: 1.5536x; 1.2265x over previous
//
#include <hip/hip_runtime.h>

// MultiHeadSelfAttention: B=4, S=2048, E=1024, H=16, Dh=64.
// Stage 0: to_bf16   -> X (and W's if ws room) converted to bf16 once
// Stage 1: qkv_gemm  -> m97-style async-staged GEMM; q,k head-major, V transposed
// Stage 2: attn      -> double-buffered LDS K/V, swapped QK^T, zero-shuffle P
//                       (key-permuted PV), one barrier per K-block
// Stage 3: out_gemm  -> m97-style async-staged GEMM @ Wo^T + bo -> fp32

typedef __bf16 bf16;
typedef __attribute__((ext_vector_type(8))) short short8;
typedef __attribute__((ext_vector_type(4))) float floatx4;
typedef __attribute__((ext_vector_type(2))) unsigned int uintx2;
typedef __attribute__((ext_vector_type(4))) unsigned int uintx4;

#define MFMA16(a, b, c) __builtin_amdgcn_mfma_f32_16x16x32_bf16((a), (b), (c), 0, 0, 0)

#define LDS_STRIDE 56   // fallback B staging: rows padded 32->56 elems, 16B-aligned

__device__ __forceinline__ float fast_exp2(float x) {
    float r;
    asm("v_exp_f32 %0, %1" : "=v"(r) : "v"(x));
    return r;
}
__device__ __forceinline__ unsigned int cvt_pk_bf16(float lo, float hi) {
    unsigned int r;
    asm("v_cvt_pk_bf16_f32 %0, %1, %2" : "=v"(r) : "v"(lo), "v"(hi));
    return r;
}

// async global->LDS, 16B per lane. lds base MUST be wave-uniform (SGPR);
// HW adds lane*16. Caller passes a base built from readfirstlane'd wave id.
__device__ __forceinline__ void async16(const bf16* __restrict__ g, short* l) {
    __builtin_amdgcn_global_load_lds((const __attribute__((address_space(1))) void*)g,
                                     (__attribute__((address_space(3))) void*)l, 16, 0, 0);
}

// 8 contiguous elements -> 8 bf16 (as short8 bit pattern)
__device__ __forceinline__ short8 frag8(const bf16* __restrict__ p) {
    return *(const short8*)p;
}
__device__ __forceinline__ short8 frag8(const float* __restrict__ p) {
    const floatx4 a = *(const floatx4*)p;
    const floatx4 b = *(const floatx4*)(p + 4);
    short8 r;
#pragma unroll
    for (int j = 0; j < 4; j++) {
        r[j]     = __builtin_bit_cast(short, (bf16)a[j]);
        r[4 + j] = __builtin_bit_cast(short, (bf16)b[j]);
    }
    return r;
}

// ---------------------------------------------------------------------------
// Stage 0: fp32 -> bf16 bulk convert. Each thread: 8 elems.
// ---------------------------------------------------------------------------
__global__ __launch_bounds__(256) void to_bf16(
    const float* __restrict__ in, bf16* __restrict__ out, int n8)
{
    const int i = blockIdx.x * 256 + threadIdx.x;
    if (i >= n8) return;
    const floatx4 a = *(const floatx4*)(in + (size_t)i * 8);
    const floatx4 b = *(const floatx4*)(in + (size_t)i * 8 + 4);
    short8 r;
#pragma unroll
    for (int j = 0; j < 4; j++) {
        r[j]     = __builtin_bit_cast(short, (bf16)a[j]);
        r[4 + j] = __builtin_bit_cast(short, (bf16)b[j]);
    }
    *(short8*)((short*)out + (size_t)i * 8) = r;
}

// ---------------------------------------------------------------------------
// m97-style 128x128 GEMM core (unchanged from R4/R5 — verified).
// ---------------------------------------------------------------------------
template <typename TB>
__device__ __forceinline__ void gemm128_async(
    const bf16* __restrict__ A, const TB* __restrict__ B,
    int m0, int n0, short* As, short* Bs, floatx4 acc[4][4])
{
    constexpr bool BASYNC = (sizeof(TB) == 2);
    const int tid  = threadIdx.x;
    const int lane = tid & 63;
    const int w    = tid >> 6;
    const int wu   = __builtin_amdgcn_readfirstlane(w);
    const int wm   = w >> 1, wn = w & 1;
    const int g    = lane >> 4, c = lane & 15;
    const int ar = lane >> 2;
    const int aq = ((lane & 3) ^ (ar & 3)) * 8;
    const int lrow = tid >> 2;
    const int lc8  = (tid & 3) * 8;

#pragma unroll
    for (int mi = 0; mi < 4; mi++)
#pragma unroll
        for (int ni = 0; ni < 4; ni++)
            acc[mi][ni] = (floatx4){0.f, 0.f, 0.f, 0.f};

    const int aswz = (g ^ (c & 3)) * 8;

    for (int k0 = 0; k0 < 1024; k0 += 32) {
        async16(A + (size_t)(m0 + w * 32 + ar) * 1024 + k0 + aq,      As + wu * 1024);
        async16(A + (size_t)(m0 + w * 32 + 16 + ar) * 1024 + k0 + aq, As + wu * 1024 + 512);
        if constexpr (BASYNC) {
            const bf16* Bb = (const bf16*)B;
            async16(Bb + (size_t)(n0 + w * 32 + ar) * 1024 + k0 + aq,      Bs + wu * 1024);
            async16(Bb + (size_t)(n0 + w * 32 + 16 + ar) * 1024 + k0 + aq, Bs + wu * 1024 + 512);
        } else {
            *(short8*)(Bs + lrow * LDS_STRIDE + lc8) =
                frag8(B + (size_t)(n0 + lrow) * 1024 + k0 + lc8);
            *(short8*)(Bs + (lrow + 64) * LDS_STRIDE + lc8) =
                frag8(B + (size_t)(n0 + lrow + 64) * 1024 + k0 + lc8);
        }
        __syncthreads();

        short8 af[4], bfr[4];
#pragma unroll
        for (int mi = 0; mi < 4; mi++)
            af[mi] = *(const short8*)(As + (wm * 64 + mi * 16 + c) * 32 + aswz);
#pragma unroll
        for (int ni = 0; ni < 4; ni++) {
            if constexpr (BASYNC)
                bfr[ni] = *(const short8*)(Bs + (wn * 64 + ni * 16 + c) * 32 + aswz);
            else
                bfr[ni] = *(const short8*)(Bs + (wn * 64 + ni * 16 + c) * LDS_STRIDE + g * 8);
        }
#pragma unroll
        for (int mi = 0; mi < 4; mi++)
#pragma unroll
            for (int ni = 0; ni < 4; ni++)
                acc[mi][ni] = MFMA16(af[mi], bfr[ni], acc[mi][ni]);
        __syncthreads();
    }
}

// ---------------------------------------------------------------------------
// Stage 1: q/k/v = x @ W{q,k,v}^T + b, scattered to head-major bf16.
// q,k: [bh][s][64].  v: TRANSPOSED [bh][d][2048].
// ---------------------------------------------------------------------------
template <typename TB>
__global__ __launch_bounds__(256) void qkv_gemm(
    const bf16* __restrict__ Xb,
    const TB* __restrict__ Wq, const TB* __restrict__ Wk, const TB* __restrict__ Wv,
    const float* __restrict__ bq, const float* __restrict__ bk, const float* __restrict__ bv,
    bf16* __restrict__ qkv)
{
    __shared__ __align__(16) short As[128 * 32];
    __shared__ __align__(16) short Bs[(sizeof(TB) == 2) ? 128 * 32 : 128 * LDS_STRIDE];

    const int z = blockIdx.z;
    const TB* W       = (z == 0) ? Wq : (z == 1) ? Wk : Wv;
    const float* bias = (z == 0) ? bq : (z == 1) ? bk : bv;
    bf16* outz = qkv + (size_t)z * (8192u * 1024u);

    const int m0 = blockIdx.y * 128;
    const int n0 = blockIdx.x * 128;

    floatx4 acc[4][4];
    gemm128_async(Xb, W, m0, n0, As, Bs, acc);

    const int lane = threadIdx.x & 63;
    const int w = threadIdx.x >> 6;
    const int wm = w >> 1, wn = w & 1;
    const int g = lane >> 4, c = lane & 15;

#pragma unroll
    for (int ni = 0; ni < 4; ni++) {
        const int n = n0 + wn * 64 + ni * 16 + c;
        const float bb = bias[n];
        const int h = n >> 6, d = n & 63;
#pragma unroll
        for (int mi = 0; mi < 4; mi++) {
#pragma unroll
            for (int r = 0; r < 4; r++) {
                const int m = m0 + wm * 64 + mi * 16 + g * 4 + r;
                const int b = m >> 11, s = m & 2047;
                const size_t idx = (z == 2)
                    ? ((((size_t)((b << 4) | h)) * 64 + d) * 2048 + s)    // V^T
                    : ((((size_t)((b << 4) | h)) * 2048 + s) * 64 + d);   // Q,K
                outz[idx] = (bf16)(acc[mi][ni][r] + bb);
            }
        }
    }
}

// ---------------------------------------------------------------------------
// Stage 2: flash attention. grid (16,64), block 256 (4 waves), XCD-sliced.
// Double-buffered LDS K/V: stage tile kb+1 (global_load_lds) BEFORE computing
// tile kb; single barrier per iteration publishes the prefetch.
// Swapped QK^T leaves P[key][q=c] lane-local; PV uses a key permutation
// pi(t,8g+j)=16(2t+(j>>2))+4g+(j&3) so the A-fragment is exactly the packed
// words {lo[2t],hi[2t],lo[2t+1],hi[2t+1]} already in the lane (ZERO shuffles);
// V-fragments are two chunk-swizzled ds_read_b64 per (t,di).
// LDS = 64 KB -> 2 blocks/CU.
// ---------------------------------------------------------------------------
__global__ __launch_bounds__(256, 2) void attn_kernel(
    const bf16* __restrict__ qkv, bf16* __restrict__ attn_out)
{
    __shared__ __align__(16) short Ks[2][128 * 64];   // [key][d], chunk^=(row&7)
    __shared__ __align__(16) short Vs[2][64 * 128];   // [d][key], chunk^=(row&15)

    const int linear = blockIdx.y * gridDim.x + blockIdx.x;
    const int slot = linear >> 3;
    const int bh = (linear & 7) * 8 + (slot >> 4);            // 0..63
    const int q0 = (slot & 15) * 128;

    const size_t HSTRIDE = 2048u * 64u;
    const bf16* __restrict__ Q  = qkv + (size_t)bh * HSTRIDE;
    const bf16* __restrict__ Kp = qkv + 8192u * 1024u + (size_t)bh * HSTRIDE;
    const bf16* __restrict__ Vt = qkv + 2u * 8192u * 1024u + (size_t)bh * HSTRIDE; // [64][2048]

    const int tid  = threadIdx.x;
    const int lane = tid & 63;
    const int w    = tid >> 6;
    const int wu   = __builtin_amdgcn_readfirstlane(w);
    const int g    = lane >> 4, c = lane & 15;

    const float C2 = 0.04508422002778f;  // (1/sqrt(1024)) * log2(e)

    // staging source maps (per-lane, loop-invariant)
    const int krow_off = lane >> 3;                 // K: 8 rows per async16
    const int kchunk   = (lane & 7) ^ (lane >> 3);  // source chunk (involution)
    const int vrow_off = lane >> 4;                 // V: 4 rows per async16

    // Q fragments resident in regs (B operand in swapped QK^T)
    short8 qf[2][2];
#pragma unroll
    for (int qb = 0; qb < 2; qb++)
#pragma unroll
        for (int ks = 0; ks < 2; ks++)
            qf[qb][ks] = *(const short8*)(Q + (size_t)(q0 + w * 32 + qb * 16 + c) * 64
                                            + ks * 32 + g * 8);

    floatx4 o[2][4];
#pragma unroll
    for (int mi = 0; mi < 2; mi++)
#pragma unroll
        for (int di = 0; di < 4; di++)
            o[mi][di] = (floatx4){0.f, 0.f, 0.f, 0.f};
    float m_run[2] = {-1e30f, -1e30f};
    float l_run[2] = {0.f, 0.f};

    // prologue: stage tile 0 into buffer 0
#pragma unroll
    for (int s = 0; s < 4; s++) {
        const int row = w * 32 + s * 8 + krow_off;
        async16(Kp + (size_t)row * 64 + kchunk * 8, &Ks[0][(wu * 32 + s * 8) * 64]);
    }
#pragma unroll
    for (int s = 0; s < 4; s++) {
        const int row = w * 16 + s * 4 + vrow_off;
        const int vchunk = (lane & 15) ^ (row & 15);
        async16(Vt + (size_t)row * 2048 + vchunk * 8, &Vs[0][(wu * 16 + s * 4) * 128]);
    }
    __syncthreads();   // drains vmcnt -> tile 0 visible

    int cur = 0;
    for (int kb = 0; kb < 16; kb++) {
        // issue prefetch of tile kb+1 into the other buffer (overlaps compute)
        if (kb < 15) {
            const int kn = (kb + 1) * 128;
#pragma unroll
            for (int s = 0; s < 4; s++) {
                const int row = w * 32 + s * 8 + krow_off;
                async16(Kp + (size_t)(kn + row) * 64 + kchunk * 8,
                        &Ks[cur ^ 1][(wu * 32 + s * 8) * 64]);
            }
#pragma unroll
            for (int s = 0; s < 4; s++) {
                const int row = w * 16 + s * 4 + vrow_off;
                const int vchunk = (lane & 15) ^ (row & 15);
                async16(Vt + (size_t)row * 2048 + kn + vchunk * 8,
                        &Vs[cur ^ 1][(wu * 16 + s * 4) * 128]);
            }
        }

        const short* __restrict__ Kc = &Ks[cur][0];
        const short* __restrict__ Vc = &Vs[cur][0];

        // S^T = K Q^T from LDS: lane (g,c) holds S[key=16ni+4g+r][q=qb*16+c]
        floatx4 sAcc[2][8];
#pragma unroll
        for (int qb = 0; qb < 2; qb++)
#pragma unroll
            for (int ni = 0; ni < 8; ni++)
                sAcc[qb][ni] = (floatx4){0.f, 0.f, 0.f, 0.f};
#pragma unroll
        for (int ks = 0; ks < 2; ks++)
#pragma unroll
            for (int ni = 0; ni < 8; ni++) {
                const short8 kf = *(const short8*)(
                    Kc + (16 * ni + c) * 64 + (((ks * 4 + g) ^ (c & 7)) * 8));
                sAcc[0][ni] = MFMA16(kf, qf[0][ks], sAcc[0][ni]);
                sAcc[1][ni] = MFMA16(kf, qf[1][ks], sAcc[1][ni]);
            }

        // online softmax + bf16 pack (lo/hi word pairs, kept in regs)
        float alpha[2];
        unsigned int lo[2][8], hi[2][8];
#pragma unroll
        for (int qb = 0; qb < 2; qb++) {
            floatx4 mv = sAcc[qb][0];
#pragma unroll
            for (int ni = 1; ni < 8; ni++)
#pragma unroll
                for (int r = 0; r < 4; r++) mv[r] = fmaxf(mv[r], sAcc[qb][ni][r]);
            float mx = fmaxf(fmaxf(mv[0], mv[1]), fmaxf(mv[2], mv[3]));
            mx = fmaxf(mx, __shfl_xor(mx, 16));
            mx = fmaxf(mx, __shfl_xor(mx, 32));
            const float mnew = fmaxf(m_run[qb], mx * C2);
            alpha[qb] = fast_exp2(m_run[qb] - mnew);
            m_run[qb] = mnew;

            floatx4 sv = {0.f, 0.f, 0.f, 0.f};
#pragma unroll
            for (int ni = 0; ni < 8; ni++) {
#pragma unroll
                for (int r = 0; r < 4; r++) {
                    const float p = fast_exp2(fmaf(sAcc[qb][ni][r], C2, -mnew));
                    sAcc[qb][ni][r] = p;
                    sv[r] += p;
                }
                lo[qb][ni] = cvt_pk_bf16(sAcc[qb][ni][0], sAcc[qb][ni][1]);
                hi[qb][ni] = cvt_pk_bf16(sAcc[qb][ni][2], sAcc[qb][ni][3]);
            }
            float sum = (sv[0] + sv[1]) + (sv[2] + sv[3]);
            sum += __shfl_xor(sum, 16);
            sum += __shfl_xor(sum, 32);
            l_run[qb] = l_run[qb] * alpha[qb] + sum;
        }

        // rescale O by per-row alpha (row 4g+r's stats live at lane with c == 4g+r)
#pragma unroll
        for (int mi = 0; mi < 2; mi++)
#pragma unroll
            for (int r = 0; r < 4; r++) {
                const int src = (lane & 48) | (g * 4 + r);
                const float a = __shfl(alpha[mi], src);
#pragma unroll
                for (int di = 0; di < 4; di++) o[mi][di][r] *= a;
            }

        // O += P V with key permutation pi(t,8g+j)=16(2t+(j>>2))+4g+(j&3):
        // A-fragment = lane-local packed words; B-fragment = two b64 reads of
        // physical keys {32t+4g+0..3, 32t+16+4g+0..3} (chunk-XOR swizzled).
#pragma unroll
        for (int t = 0; t < 4; t++) {
            const short8 pf0 = __builtin_bit_cast(short8,
                (uintx4){lo[0][2 * t], hi[0][2 * t], lo[0][2 * t + 1], hi[0][2 * t + 1]});
            const short8 pf1 = __builtin_bit_cast(short8,
                (uintx4){lo[1][2 * t], hi[1][2 * t], lo[1][2 * t + 1], hi[1][2 * t + 1]});
#pragma unroll
            for (int di = 0; di < 4; di++) {
                const int rowb = (16 * di + c) * 128 + 4 * (g & 1);
                const uintx2 vlo = *(const uintx2*)(
                    Vc + rowb + (((4 * t + (g >> 1)) ^ c) * 8));
                const uintx2 vhi = *(const uintx2*)(
                    Vc + rowb + (((4 * t + 2 + (g >> 1)) ^ c) * 8));
                const short8 vf = __builtin_bit_cast(short8,
                    (uintx4){vlo[0], vlo[1], vhi[0], vhi[1]});
                o[0][di] = MFMA16(pf0, vf, o[0][di]);
                o[1][di] = MFMA16(pf1, vf, o[1][di]);
            }
        }

        if (kb < 15) __syncthreads();   // publish prefetch + protect buffers
        cur ^= 1;
    }

    // epilogue: O /= l (redistribute l to O's row layout), write bf16
    const int b = bh >> 4, h = bh & 15;
#pragma unroll
    for (int mi = 0; mi < 2; mi++) {
#pragma unroll
        for (int r = 0; r < 4; r++) {
            const int src = (lane & 48) | (g * 4 + r);
            const float linv = 1.0f / __shfl(l_run[mi], src);
            const int srow = q0 + w * 32 + mi * 16 + g * 4 + r;
#pragma unroll
            for (int di = 0; di < 4; di++) {
                attn_out[((size_t)(b * 2048 + srow)) * 1024 + h * 64 + di * 16 + c] =
                    (bf16)(o[mi][di][r] * linv);
            }
        }
    }
}

// ---------------------------------------------------------------------------
// Stage 3: out = attn @ Wo^T + bo -> fp32. grid (8, 64).
// ---------------------------------------------------------------------------
template <typename TB>
__global__ __launch_bounds__(256) void out_gemm(
    const bf16* __restrict__ A, const TB* __restrict__ Wo,
    const float* __restrict__ bo, float* __restrict__ C)
{
    __shared__ __align__(16) short As[128 * 32];
    __shared__ __align__(16) short Bs[(sizeof(TB) == 2) ? 128 * 32 : 128 * LDS_STRIDE];

    const int m0 = blockIdx.y * 128;
    const int n0 = blockIdx.x * 128;

    floatx4 acc[4][4];
    gemm128_async(A, Wo, m0, n0, As, Bs, acc);

    const int lane = threadIdx.x & 63;
    const int w = threadIdx.x >> 6;
    const int wm = w >> 1, wn = w & 1;
    const int g = lane >> 4, c = lane & 15;

#pragma unroll
    for (int ni = 0; ni < 4; ni++) {
        const int n = n0 + wn * 64 + ni * 16 + c;
        const float bb = bo[n];
#pragma unroll
        for (int mi = 0; mi < 4; mi++) {
#pragma unroll
            for (int r = 0; r < 4; r++) {
                const int m = m0 + wm * 64 + mi * 16 + g * 4 + r;
                C[(size_t)m * 1024 + n] = acc[mi][ni][r] + bb;
            }
        }
    }
}

// ---------------------------------------------------------------------------
extern "C" void kernel_launch(void* const* d_in, const int* in_sizes, int n_in,
                              void* d_out, int out_size, void* d_ws, size_t ws_size,
                              hipStream_t stream)
{
    const float* x  = (const float*)d_in[0];
    const float* Wq = (const float*)d_in[1];
    const float* bq = (const float*)d_in[2];
    const float* Wk = (const float*)d_in[3];
    const float* bk = (const float*)d_in[4];
    const float* Wv = (const float*)d_in[5];
    const float* bv = (const float*)d_in[6];
    const float* Wo = (const float*)d_in[7];
    const float* bo = (const float*)d_in[8];
    float* out = (float*)d_out;

    bf16* qkv  = (bf16*)d_ws;                       // 3 x 8192x1024 bf16 = 48 MB
    bf16* attn = qkv + 3u * 8192u * 1024u;          // 8192x1024 bf16 = 16 MB
    bf16* xb   = attn;   // X-bf16 aliases attn region (dead before attn written)

    const size_t base = 64u * 1024u * 1024u;
    const bool haveW = ws_size >= base + 8u * 1024u * 1024u;
    bf16* wb = (bf16*)((char*)d_ws + base);         // 4 x 1024x1024 bf16 = 8 MB

    to_bf16<<<dim3(4096), dim3(256), 0, stream>>>(x, xb, 1048576);

    if (haveW) {
        to_bf16<<<dim3(512), dim3(256), 0, stream>>>(Wq, wb + 0u * 1048576u, 131072);
        to_bf16<<<dim3(512), dim3(256), 0, stream>>>(Wk, wb + 1u * 1048576u, 131072);
        to_bf16<<<dim3(512), dim3(256), 0, stream>>>(Wv, wb + 2u * 1048576u, 131072);
        to_bf16<<<dim3(512), dim3(256), 0, stream>>>(Wo, wb + 3u * 1048576u, 131072);
        qkv_gemm<bf16><<<dim3(8, 64, 3), dim3(256), 0, stream>>>(
            xb, wb, wb + 1048576u, wb + 2u * 1048576u, bq, bk, bv, qkv);
    } else {
        qkv_gemm<float><<<dim3(8, 64, 3), dim3(256), 0, stream>>>(
            xb, Wq, Wk, Wv, bq, bk, bv, qkv);
    }

    attn_kernel<<<dim3(16, 64), dim3(256), 0, stream>>>(qkv, attn);

    if (haveW) {
        out_gemm<bf16><<<dim3(8, 64), dim3(256), 0, stream>>>(
            attn, wb + 3u * 1048576u, bo, out);
    } else {
        out_gemm<float><<<dim3(8, 64), dim3(256), 0, stream>>>(attn, Wo, bo, out);
    }
}